// Round 1
// baseline (1877.749 us; speedup 1.0000x reference)
//
#include <hip/hip_runtime.h>
#include <hip/hip_fp16.h>

#define NTOK   49
#define DIMM   384
#define NHEAD  12
#define HD     32
#define BNWIN  4096        // 64 windows * 64 batch
#define MROWS  200704      // BNWIN * NTOK

typedef _Float16 half8 __attribute__((ext_vector_type(8)));
typedef float    f32x4 __attribute__((ext_vector_type(4)));

// workspace layout (byte offsets, all 256-aligned)
#define WQH_OFF   0u          // 442368 halves  (884736 B)
#define WPH_OFF   884736u     // 147456 halves  (294912 B)
#define RB_OFF    1179648u    // 28812 floats   (115248 B)
#define CTX_OFF   1310720u    // 77070336 halves (154140672 B)

// ---------------------------------------------------------------------------
// Kernel 0: fp32->fp16 weight conversion + relative-position-bias pregather
// ---------------------------------------------------------------------------
__global__ __launch_bounds__(256) void prep_kernel(
    const float* __restrict__ wqkv, const float* __restrict__ wproj,
    const float* __restrict__ btab,
    _Float16* __restrict__ wq_h, _Float16* __restrict__ wp_h,
    float* __restrict__ rb)
{
    int idx = blockIdx.x * 256 + threadIdx.x;
    if (idx < 442368) wq_h[idx] = (_Float16)wqkv[idx];
    if (idx < 147456) wp_h[idx] = (_Float16)wproj[idx];
    if (idx < 28812) {
        int h  = idx / 2401;
        int ij = idx - h * 2401;
        int i  = ij / 49;
        int j  = ij - i * 49;
        int ih = i / 7, iw = i - ih * 7;
        int jh = j / 7, jw = j - jh * 7;
        int rel = (ih - jh + 6) * 13 + (iw - jw + 6);
        rb[idx] = btab[rel * 12 + h];
    }
}

// ---------------------------------------------------------------------------
// Kernel 1: fused QKV projection + windowed attention (one block per window)
// 256 threads = 4 waves; wave w owns heads {w, w+4, w+8}; no barriers.
// ---------------------------------------------------------------------------
__global__ __launch_bounds__(256) void attn_kernel(
    const float* __restrict__ x, const float* __restrict__ mask,
    const _Float16* __restrict__ wq, const float* __restrict__ bq,
    const float* __restrict__ rb, _Float16* __restrict__ ctx)
{
    // per-wave LDS (halves): [0,1960) q (49x40), [1960,3920) k (49x40)
    //                        [0,3528)  p (49x72)  -- aliases q/k after use
    //                        [3920,6224) vT (32 rows d x 72 cols j)
    __shared__ _Float16 smem[4][6224];
    const int tid  = threadIdx.x;
    const int wv   = tid >> 6;
    const int lane = tid & 63;
    const int quad = lane >> 4;
    const int l16  = lane & 15;
    const int bn   = blockIdx.x;
    const int wm   = bn >> 6;          // window index (B=64)

    _Float16* q_s  = &smem[wv][0];
    _Float16* k_s  = &smem[wv][1960];
    _Float16* p_s  = &smem[wv][0];
    _Float16* vT_s = &smem[wv][3920];

    const float scale = 0.17677669529663687f;  // 32^-0.5

    int rowm[4];
#pragma unroll
    for (int mi = 0; mi < 4; ++mi) {
        int r = mi * 16 + l16;
        rowm[mi] = r > 48 ? 48 : r;    // clamp: rows >=49 are finite clones of row 48
    }

    for (int hh = 0; hh < 3; ++hh) {
        const int h = wv + (hh << 2);

        // ---- phase 1: per-head QKV mini-GEMM (96 cols), K=384 ----
        f32x4 acc[6][4];
#pragma unroll
        for (int nn = 0; nn < 6; ++nn)
#pragma unroll
            for (int mi = 0; mi < 4; ++mi)
                acc[nn][mi] = (f32x4){0.f, 0.f, 0.f, 0.f};

        for (int k = 0; k < 12; ++k) {
            half8 af[4];
#pragma unroll
            for (int mi = 0; mi < 4; ++mi) {
                const float* ap = x + ((size_t)bn * NTOK + rowm[mi]) * DIMM + k * 32 + quad * 8;
                float4 a0 = *(const float4*)ap;
                float4 a1 = *(const float4*)(ap + 4);
                half8 t;
                t[0] = (_Float16)a0.x; t[1] = (_Float16)a0.y;
                t[2] = (_Float16)a0.z; t[3] = (_Float16)a0.w;
                t[4] = (_Float16)a1.x; t[5] = (_Float16)a1.y;
                t[6] = (_Float16)a1.z; t[7] = (_Float16)a1.w;
                af[mi] = t;
            }
#pragma unroll
            for (int nn = 0; nn < 6; ++nn) {
                const int n0 = (nn >> 1) * DIMM + h * HD + (nn & 1) * 16;
                half8 bf = *(const half8*)(wq + (size_t)(n0 + l16) * DIMM + k * 32 + quad * 8);
#pragma unroll
                for (int mi = 0; mi < 4; ++mi)
                    acc[nn][mi] = __builtin_amdgcn_mfma_f32_16x16x32_f16(af[mi], bf, acc[nn][mi], 0, 0, 0);
            }
        }
        // bias add + scatter to wave-private LDS (q/k row-major, v transposed)
#pragma unroll
        for (int nn = 0; nn < 6; ++nn) {
            const int n0 = (nn >> 1) * DIMM + h * HD + (nn & 1) * 16;
            const float bias = bq[n0 + l16];
            const int colh = (nn & 1) * 16 + l16;
#pragma unroll
            for (int mi = 0; mi < 4; ++mi) {
#pragma unroll
                for (int r = 0; r < 4; ++r) {
                    const int row = mi * 16 + quad * 4 + r;
                    const float v = acc[nn][mi][r] + bias;
                    if (nn < 2) {
                        if (row < 49) q_s[row * 40 + colh] = (_Float16)v;
                    } else if (nn < 4) {
                        if (row < 49) k_s[row * 40 + colh] = (_Float16)v;
                    } else {
                        vT_s[colh * 72 + row] = (_Float16)v;  // rows>=49: finite clones, P=0 there
                    }
                }
            }
        }

        // ---- phase 2: S = q @ k^T  (K=32, single MFMA step per tile) ----
        f32x4 s[4][4];
        {
            half8 bk[4];
#pragma unroll
            for (int nj = 0; nj < 4; ++nj)
                bk[nj] = *(const half8*)(k_s + rowm[nj] * 40 + quad * 8);
#pragma unroll
            for (int mi = 0; mi < 4; ++mi) {
                half8 aq = *(const half8*)(q_s + rowm[mi] * 40 + quad * 8);
#pragma unroll
                for (int nj = 0; nj < 4; ++nj)
                    s[mi][nj] = __builtin_amdgcn_mfma_f32_16x16x32_f16(
                        aq, bk[nj], (f32x4){0.f, 0.f, 0.f, 0.f}, 0, 0, 0);
            }
        }

        // ---- phase 3: scale + rel-bias + mask, register softmax, P -> LDS ----
        const float* rbh = rb + h * 2401;
        const float* mkw = mask + wm * 2401;
#pragma unroll
        for (int mi = 0; mi < 4; ++mi) {
#pragma unroll
            for (int r = 0; r < 4; ++r) {
                const int i  = mi * 16 + quad * 4 + r;
                const int iq = i > 48 ? 48 : i;
                float vals[4];
                float mx = -3.0e38f;
#pragma unroll
                for (int nj = 0; nj < 4; ++nj) {
                    const int j = nj * 16 + l16;
                    float v = -1.0e30f;
                    if (j < 49)
                        v = s[mi][nj][r] * scale + rbh[iq * 49 + j] + mkw[iq * 49 + j];
                    vals[nj] = v;
                    mx = fmaxf(mx, v);
                }
#pragma unroll
                for (int off = 8; off >= 1; off >>= 1)
                    mx = fmaxf(mx, __shfl_xor(mx, off));
                float sum = 0.f;
#pragma unroll
                for (int nj = 0; nj < 4; ++nj) {
                    vals[nj] = __expf(vals[nj] - mx);
                    sum += vals[nj];
                }
#pragma unroll
                for (int off = 8; off >= 1; off >>= 1)
                    sum += __shfl_xor(sum, off);
                const float inv = __builtin_amdgcn_rcpf(sum);
                if (i < 49) {
#pragma unroll
                    for (int nj = 0; nj < 4; ++nj)
                        p_s[i * 72 + nj * 16 + l16] = (_Float16)(vals[nj] * inv);
                }
            }
        }

        // ---- phase 4: O = P @ V ----
        f32x4 o[4][2];
#pragma unroll
        for (int mi = 0; mi < 4; ++mi)
#pragma unroll
            for (int nd = 0; nd < 2; ++nd)
                o[mi][nd] = (f32x4){0.f, 0.f, 0.f, 0.f};
#pragma unroll
        for (int ks = 0; ks < 2; ++ks) {
            half8 bv[2];
#pragma unroll
            for (int nd = 0; nd < 2; ++nd)
                bv[nd] = *(const half8*)(vT_s + (nd * 16 + l16) * 72 + ks * 32 + quad * 8);
#pragma unroll
            for (int mi = 0; mi < 4; ++mi) {
                half8 apf = *(const half8*)(p_s + rowm[mi] * 72 + ks * 32 + quad * 8);
#pragma unroll
                for (int nd = 0; nd < 2; ++nd)
                    o[mi][nd] = __builtin_amdgcn_mfma_f32_16x16x32_f16(apf, bv[nd], o[mi][nd], 0, 0, 0);
            }
        }

        // ---- phase 5: ctx out (fp16, [bn*49+i][h*32+d]) ----
#pragma unroll
        for (int mi = 0; mi < 4; ++mi) {
#pragma unroll
            for (int r = 0; r < 4; ++r) {
                const int i = mi * 16 + quad * 4 + r;
                if (i < 49) {
#pragma unroll
                    for (int nd = 0; nd < 2; ++nd) {
                        const int col = h * HD + nd * 16 + l16;
                        ctx[((size_t)bn * NTOK + i) * DIMM + col] = (_Float16)o[mi][nd][r];
                    }
                }
            }
        }
    }
}

// ---------------------------------------------------------------------------
// Kernel 2: out = ctx @ w_proj^T + b_proj   [200704,384]x[384,384]
// block = 64 rows x 384 cols; 4 waves, wave w covers cols [w*96, w*96+96)
// ---------------------------------------------------------------------------
__global__ __launch_bounds__(256) void proj_kernel(
    const _Float16* __restrict__ ctx, const _Float16* __restrict__ wp,
    const float* __restrict__ bp, float* __restrict__ out)
{
    const int tid  = threadIdx.x;
    const int wv   = tid >> 6;
    const int lane = tid & 63;
    const int quad = lane >> 4;
    const int l16  = lane & 15;
    const size_t m0 = (size_t)blockIdx.x * 64;

    f32x4 c[4][6];
#pragma unroll
    for (int mi = 0; mi < 4; ++mi)
#pragma unroll
        for (int nj = 0; nj < 6; ++nj)
            c[mi][nj] = (f32x4){0.f, 0.f, 0.f, 0.f};

    for (int k = 0; k < 12; ++k) {
        half8 a[4];
#pragma unroll
        for (int mi = 0; mi < 4; ++mi)
            a[mi] = *(const half8*)(ctx + (m0 + mi * 16 + l16) * DIMM + k * 32 + quad * 8);
#pragma unroll
        for (int nj = 0; nj < 6; ++nj) {
            const int n = wv * 96 + nj * 16 + l16;
            half8 b = *(const half8*)(wp + (size_t)n * DIMM + k * 32 + quad * 8);
#pragma unroll
            for (int mi = 0; mi < 4; ++mi)
                c[mi][nj] = __builtin_amdgcn_mfma_f32_16x16x32_f16(a[mi], b, c[mi][nj], 0, 0, 0);
        }
    }
#pragma unroll
    for (int nj = 0; nj < 6; ++nj) {
        const int n = wv * 96 + nj * 16 + l16;
        const float bias = bp[n];
#pragma unroll
        for (int mi = 0; mi < 4; ++mi) {
#pragma unroll
            for (int r = 0; r < 4; ++r) {
                const size_t row = m0 + mi * 16 + quad * 4 + r;
                out[row * DIMM + n] = c[mi][nj][r] + bias;
            }
        }
    }
}

// ---------------------------------------------------------------------------
extern "C" void kernel_launch(void* const* d_in, const int* in_sizes, int n_in,
                              void* d_out, int out_size, void* d_ws, size_t ws_size,
                              hipStream_t stream)
{
    const float* x     = (const float*)d_in[0];
    const float* mask  = (const float*)d_in[1];
    const float* wqkv  = (const float*)d_in[2];
    const float* bqkv  = (const float*)d_in[3];
    const float* wproj = (const float*)d_in[4];
    const float* bproj = (const float*)d_in[5];
    const float* btab  = (const float*)d_in[6];
    float* out = (float*)d_out;

    char* ws = (char*)d_ws;
    _Float16* wq_h = (_Float16*)(ws + WQH_OFF);
    _Float16* wp_h = (_Float16*)(ws + WPH_OFF);
    float*    rb   = (float*)(ws + RB_OFF);
    _Float16* ctx  = (_Float16*)(ws + CTX_OFF);

    hipLaunchKernelGGL(prep_kernel, dim3(1728), dim3(256), 0, stream,
                       wqkv, wproj, btab, wq_h, wp_h, rb);
    hipLaunchKernelGGL(attn_kernel, dim3(BNWIN), dim3(256), 0, stream,
                       x, mask, wq_h, bqkv, rb, ctx);
    hipLaunchKernelGGL(proj_kernel, dim3(MROWS / 64), dim3(256), 0, stream,
                       ctx, wp_h, bproj, out);
}